// Round 11
// baseline (37.592 us; speedup 1.0000x reference)
//
#include <hip/hip_runtime.h>
#include <hip/hip_fp8.h>

#define N_E   512
#define DIM   64
#define HW    4096        // 64*64
#define CHW   (64*HW)     // 262144
#define NPIX  131072      // 32*64*64

typedef __attribute__((ext_vector_type(4))) float f32x4;

__device__ __forceinline__ unsigned char f2e4m3(float x) {
    __hip_fp8_e4m3 t(x);
    return (unsigned char)t.__x;
}
__device__ __forceinline__ float e4m3tof(unsigned char b) {
    __hip_fp8_e4m3 t; t.__x = (__hip_fp8_storage_t)b;
    return (float)t;
}

// --- prep: codebook -> fp8 B-fragments (scaled x512) + consistent norms ------
// chunk g = t*128 + h*64 + lane : 8 fp8 = cb[t*16+(lane&15)][h*32+(lane>>4)*8 + j] * 512
__global__ __launch_bounds__(512) void vq_prep(
        const float* __restrict__ cb, float* __restrict__ cnh,
        uint2* __restrict__ frag, float* __restrict__ out) {
    int g   = blockIdx.x * 512 + threadIdx.x;   // 0..4095
    int t   = g >> 7;
    int h   = (g >> 6) & 1;
    int ln  = g & 63;
    const float* src = cb + (t * 16 + (ln & 15)) * DIM + h * 32 + (ln >> 4) * 8;
    unsigned lo = 0, hi = 0;
    #pragma unroll
    for (int j = 0; j < 4; ++j) lo |= (unsigned)f2e4m3(src[j]     * 512.f) << (8 * j);
    #pragma unroll
    for (int j = 0; j < 4; ++j) hi |= (unsigned)f2e4m3(src[4 + j] * 512.f) << (8 * j);
    frag[g] = make_uint2(lo, hi);

    if (blockIdx.x == 0) {
        // cn = -0.5/512 * ||c'_fp8||^2  (uses the SAME rounded values as frag)
        const float* c = cb + threadIdx.x * DIM;
        float s = 0.f;
        #pragma unroll
        for (int k = 0; k < DIM; ++k) {
            float v = e4m3tof(f2e4m3(c[k] * 512.f));
            s = fmaf(v, v, s);
        }
        cnh[threadIdx.x] = s * (-0.5f / 512.f);
        if (threadIdx.x == 0) out[0] = 0.f;
    }
}

// =============================================================================
// main: 1024 blocks x 512 thr (8 waves), 128 px/block (16 px/wave, m=1).
// LDS = 32 KB fp8 codebook + cn + idx  => 4 blocks/CU, 32 waves/CU.
// Scores via fp8 MFMA (argmax of z.c' + cn == argmin distance); loss from
// scores; zq = fp8-dequant codebook rows gathered from LDS.
// =============================================================================
__global__ __launch_bounds__(512, 8) void vq_main(
        const float* __restrict__ z, const float* __restrict__ cnh,
        const uint2* __restrict__ frag, float* __restrict__ out) {
    __shared__ uint2 Blds[4096];     // 32 KB fp8 B-fragments
    __shared__ float cn[N_E];        // 2 KB
    __shared__ int   idx_lds[128];   // chosen code per pixel
    __shared__ float red[8];

    const int tid = threadIdx.x;
    const int w   = tid >> 6;
    const int l   = tid & 63;
    const int col = l & 15;
    const int grp = l >> 4;

    const int P0  = blockIdx.x * 128;
    const int b   = P0 >> 12;
    const int hwb = P0 & 4095;
    const float* zimg = z + (size_t)b * CHW;
    float*       oimg = out + 1 + (size_t)b * CHW;

    // ---- z loads (strided scalar; latency hidden by 32 waves/CU) ----
    const float* zp = zimg + hwb + w * 16 + col;
    long long afr[2];
    float zn = 0.f;
    #pragma unroll
    for (int h = 0; h < 2; ++h) {
        float v[8];
        #pragma unroll
        for (int j = 0; j < 8; ++j) {
            v[j] = zp[(h * 32 + grp * 8 + j) * HW];
            zn = fmaf(v[j], v[j], zn);
        }
        unsigned lo = 0, hi = 0;
        #pragma unroll
        for (int j = 0; j < 4; ++j) lo |= (unsigned)f2e4m3(v[j])     << (8 * j);
        #pragma unroll
        for (int j = 0; j < 4; ++j) hi |= (unsigned)f2e4m3(v[4 + j]) << (8 * j);
        afr[h] = (long long)(((unsigned long long)hi << 32) | (unsigned long long)lo);
    }
    zn += __shfl_xor(zn, 16);
    zn += __shfl_xor(zn, 32);    // ||z||^2 for px = base+col, valid on all lanes

    // ---- stage fp8 codebook + cn -> LDS (linear, coalesced) ----
    #pragma unroll
    for (int i = 0; i < 8; ++i) Blds[tid + i * 512] = frag[tid + i * 512];
    cn[tid] = cnh[tid];
    __syncthreads();

    // ---- sweep: argmax of (z.c' + cn) == argmin distance ----
    float best[4];
    int   bid[4];
    #pragma unroll
    for (int r = 0; r < 4; ++r) { best[r] = -1e30f; bid[r] = 0; }

    const long long* B8 = (const long long*)Blds;
    #pragma unroll 2
    for (int t = 0; t < 32; ++t) {
        long long b0 = B8[t * 128 + l];
        long long b1 = B8[t * 128 + 64 + l];
        const float c0 = cn[t * 16 + col];
        f32x4 a = {c0, c0, c0, c0};
        a = __builtin_amdgcn_mfma_f32_16x16x32_fp8_fp8(afr[0], b0, a, 0, 0, 0);
        a = __builtin_amdgcn_mfma_f32_16x16x32_fp8_fp8(afr[1], b1, a, 0, 0, 0);
        #pragma unroll
        for (int r = 0; r < 4; ++r)
            if (a[r] > best[r]) { best[r] = a[r]; bid[r] = t; }
    }

    // ---- cross-lane argmax over 16 code-cols (tie -> smaller code) ----
    float ls = 0.f;
    #pragma unroll
    for (int r = 0; r < 4; ++r) {
        float s = best[r];
        int   c = bid[r] * 16 + col;
        #pragma unroll
        for (int mk = 1; mk < 16; mk <<= 1) {
            float os = __shfl_xor(s, mk);
            int   oc = __shfl_xor(c, mk);
            if (os > s || (os == s && oc < c)) { s = os; c = oc; }
        }
        float znp = __shfl(zn, grp * 16 + grp * 4 + r);
        if (col == 0) {
            ls += znp - s * (2.f / 512.f);          // exact d for picked code
            idx_lds[w * 16 + grp * 4 + r] = c;
        }
    }

    // ---- store: gather fp8 code rows from LDS, dequant, scalar stores ----
    // lane group gg = l>>4 handles channel quarter gg*16..gg*16+15 of px base+col
    const int gg  = l >> 4;
    const int qi  = idx_lds[w * 16 + col];     // same-wave producer
    const int qt  = qi >> 4;
    const int cq  = qi & 15;
    const int h2  = gg >> 1;
    const int pxg = hwb + w * 16 + col;
    #pragma unroll
    for (int s2 = 0; s2 < 2; ++s2) {
        const int grp2 = (gg & 1) * 2 + s2;
        uint2 ch = Blds[qt * 128 + h2 * 64 + grp2 * 16 + cq];
        const unsigned dw[2] = {ch.x, ch.y};
        #pragma unroll
        for (int dj = 0; dj < 2; ++dj)
            #pragma unroll
            for (int j = 0; j < 4; ++j) {
                float q = e4m3tof((unsigned char)(dw[dj] >> (8 * j))) * (1.f / 512.f);
                oimg[(h2 * 32 + grp2 * 8 + dj * 4 + j) * HW + pxg] = q;
            }
    }

    // ---- loss: wave reduce -> block -> one atomic ----
    #pragma unroll
    for (int off = 32; off; off >>= 1) ls += __shfl_down(ls, off);
    if (l == 0) red[w] = ls;
    __syncthreads();
    if (tid == 0) {
        float s = 0.f;
        #pragma unroll
        for (int i = 0; i < 8; ++i) s += red[i];
        atomicAdd(out, s * (1.25f / (float)(NPIX * DIM)));
    }
}

extern "C" void kernel_launch(void* const* d_in, const int* in_sizes, int n_in,
                              void* d_out, int out_size, void* d_ws, size_t ws_size,
                              hipStream_t stream) {
    const float* z  = (const float*)d_in[0];   // (32,64,64,64) f32
    const float* cb = (const float*)d_in[1];   // (512,64) f32
    float* out = (float*)d_out;                // [loss | zq]
    float* ws  = (float*)d_ws;
    float* cnh  = ws;                          // 512 f32
    uint2* frag = (uint2*)(ws + 512);          // 32 KB fp8 fragments

    vq_prep<<<8, 512, 0, stream>>>(cb, cnh, frag, out);
    vq_main<<<1024, 512, 0, stream>>>(z, cnh, frag, out);
}